// Round 6
// baseline (290.677 us; speedup 1.0000x reference)
//
#include <hip/hip_runtime.h>
#include <stdint.h>

// GraphConv: out = indeg^-1/2 * segsum_dst( (feat * outdeg^-1/2)[src] ) @ W
// Transform-first: h = (feat*outdeg^-1/2) @ W once (bf16, NATURAL layout),
// then aggregate h rows per dst from dst-partitioned edge buckets.
//
// R6: aggp rewritten FULL-WAVE per node (R2-R5 used half-wave -> permanent
// wave divergence: every gather ran at <=32/64 lanes). Lane l holds dims
// 2l,2l+1 (one uint = 2 bf16): per edge ONE 64x4B coalesced load + ~5 VALU.
// h back to natural layout (gemm_h epilogue = direct ushort4 stores).
// part: P4 binary search replaced by per-partition run copies; P2 1024-wide
// Hillis-Steele (40 barriers) replaced by 2 concurrent single-wave
// carry-scans (1 barrier).

#define DIM 128
#define PN 128            // nodes per dst/src partition
#define MAXPP 800         // >= NPP = ceil(100000/128) = 782
#define CAPE 2560         // edges per dst-partition (mean 2048, +11 sigma)
#define CAPS 2560         // src entries per src-partition
#define PT 512            // part threads
#define EPT 13            // edges per thread in part
#define CHUNK (PT * EPT)  // 6656 edges per part block

typedef unsigned int uint;
typedef unsigned short ushortT;

__device__ __forceinline__ ushortT f2bf(float x) {
    uint u = __float_as_uint(x);
    u = (u + 0x7FFFu + ((u >> 16) & 1u)) >> 16;   // RNE
    return (ushortT)u;
}

// ---------------- part: partition edges by dst>>7 (+ src bytes by src>>7) ---
__global__ __launch_bounds__(PT) void part(
    const int* __restrict__ src, const int* __restrict__ dst,
    int* __restrict__ curD, int* __restrict__ curS,
    int* __restrict__ pairs, unsigned char* __restrict__ srcb,
    int E, int NPP) {
    __shared__ int cD[MAXPP], cS[MAXPP];
    __shared__ int lofD[MAXPP], lofS[MAXPP];     // local exclusive offsets
    __shared__ int gbD[MAXPP], gbS[MAXPP];       // global base per partition
    __shared__ int bufD[CHUNK];                  // dst-sorted packed words
    __shared__ unsigned char bufS[CHUNK];        // src-sorted local bytes

    int tid = threadIdx.x;
    int wv = tid >> 6, l = tid & 63;
    long long base = (long long)blockIdx.x * CHUNK;
    for (int i = tid; i < NPP; i += PT) { cD[i] = 0; cS[i] = 0; }
    __syncthreads();

    // P1: count; atomicAdd return value = unique local rank (stash in regs)
    int sv[EPT], dv[EPT], lrD[EPT], lrS[EPT];
#pragma unroll
    for (int j = 0; j < EPT; ++j) {
        long long e = base + tid + j * PT;
        bool ok = e < E;
        int s = 0, d = 0;
        if (ok) { s = src[e]; d = dst[e]; }
        sv[j] = s; dv[j] = d;
        lrD[j] = ok ? atomicAdd(&cD[d >> 7], 1) : 0;
        lrS[j] = ok ? atomicAdd(&cS[s >> 7], 1) : 0;
    }
    __syncthreads();

    // P2: exclusive scans; wave0 scans cD, wave1 scans cS (concurrently)
    if (wv < 2) {
        const int* cnts = wv ? cS : cD;
        int* lof = wv ? lofS : lofD;
        int carry = 0;
        for (int b = 0; b < NPP; b += 64) {
            int i = b + l;
            int x = (i < NPP) ? cnts[i] : 0;
            int incl = x;
            for (int o = 1; o < 64; o <<= 1) {
                int y = __shfl_up(incl, o, 64);
                if (l >= o) incl += y;
            }
            if (i < NPP) lof[i] = carry + incl - x;
            carry += __shfl(incl, 63, 64);
        }
    }
    __syncthreads();

    // P2b: bulk global reservations (~2*NPP atomics per block)
    for (int i = tid; i < NPP; i += PT) {
        int c = cD[i];
        gbD[i] = c ? atomicAdd(&curD[i], c) : 0;
        c = cS[i];
        gbS[i] = c ? atomicAdd(&curS[i], c) : 0;
    }

    // P3: place edges into LDS at sorted positions (no atomics)
#pragma unroll
    for (int j = 0; j < EPT; ++j) {
        long long e = base + tid + j * PT;
        if (e < E) {
            int s = sv[j], d = dv[j];
            bufD[lofD[d >> 7] + lrD[j]] = (s << 7) | (d & 127);
            bufS[lofS[s >> 7] + lrS[j]] = (unsigned char)(s & 127);
        }
    }
    __syncthreads();

    // P4: per-partition run copies (coalesced), wave per partition
    for (int pp = wv; pp < NPP; pp += 8) {
        int lo = lofD[pp], len = cD[pp], gb = gbD[pp];
        for (int j = l; j < len; j += 64)
            if (gb + j < CAPE) pairs[(size_t)pp * CAPE + gb + j] = bufD[lo + j];
        lo = lofS[pp]; len = cS[pp]; gb = gbS[pp];
        for (int j = l; j < len; j += 64)
            if (gb + j < CAPS) srcb[(size_t)pp * CAPS + gb + j] = bufS[lo + j];
    }
}

// ---------------- deg: per-partition out-degree histogram -> oscale ---------
__global__ __launch_bounds__(256) void deg(
    const int* __restrict__ curS, const unsigned char* __restrict__ srcb,
    float* __restrict__ oscale, int N) {
    __shared__ int hist[PN];
    int p = blockIdx.x, tid = threadIdx.x;
    if (tid < PN) hist[tid] = 0;
    __syncthreads();
    int cnt = min(curS[p], CAPS);
    const unsigned char* b = &srcb[(size_t)p * CAPS];
    for (int i = tid; i < cnt; i += 256) atomicAdd(&hist[b[i]], 1);
    __syncthreads();
    if (tid < PN) {
        int node = p * PN + tid;
        if (node < N) oscale[node] = rsqrtf((float)max(hist[tid], 1));
    }
}

// ---------------- h = (feat * outdeg^-1/2) @ W  (bf16, natural layout) ------
__global__ __launch_bounds__(256) void gemm_h(
    const float* __restrict__ feat, const float* __restrict__ W,
    const float* __restrict__ oscale, ushortT* __restrict__ h, int M) {
    __shared__ float As[32][36];
    __shared__ float Bs[32][128];

    int tid = threadIdx.x;
    int m0 = blockIdx.x * 32;
    int tx = tid & 31;
    int ty = tid >> 5;
    int bc = tx << 2;

    float acc[4][4];
#pragma unroll
    for (int r = 0; r < 4; ++r)
#pragma unroll
        for (int c = 0; c < 4; ++c) acc[r][c] = 0.f;

    int am = tid >> 3;
    int ak = (tid & 7) << 2;
    int arow = m0 + am;
    float scale = (arow < M) ? oscale[arow] : 0.f;

    for (int k0 = 0; k0 < DIM; k0 += 32) {
        float4 a = make_float4(0.f, 0.f, 0.f, 0.f);
        if (arow < M) a = *(const float4*)&feat[(size_t)arow * DIM + k0 + ak];
        As[ak + 0][am] = a.x * scale;
        As[ak + 1][am] = a.y * scale;
        As[ak + 2][am] = a.z * scale;
        As[ak + 3][am] = a.w * scale;
#pragma unroll
        for (int i = 0; i < 4; ++i) {
            int k = ty + i * 8;
            *(float4*)&Bs[k][bc] = *(const float4*)&W[(size_t)(k0 + k) * DIM + bc];
        }
        __syncthreads();
#pragma unroll
        for (int k = 0; k < 32; ++k) {
            float4 a4 = *(const float4*)&As[k][ty << 2];
            float4 b4 = *(const float4*)&Bs[k][bc];
            acc[0][0] += a4.x * b4.x; acc[0][1] += a4.x * b4.y; acc[0][2] += a4.x * b4.z; acc[0][3] += a4.x * b4.w;
            acc[1][0] += a4.y * b4.x; acc[1][1] += a4.y * b4.y; acc[1][2] += a4.y * b4.z; acc[1][3] += a4.y * b4.w;
            acc[2][0] += a4.z * b4.x; acc[2][1] += a4.z * b4.y; acc[2][2] += a4.z * b4.z; acc[2][3] += a4.z * b4.w;
            acc[3][0] += a4.w * b4.x; acc[3][1] += a4.w * b4.y; acc[3][2] += a4.w * b4.z; acc[3][3] += a4.w * b4.w;
        }
        __syncthreads();
    }
    // epilogue: direct bf16 stores, natural layout (wave covers 512B runs)
#pragma unroll
    for (int r = 0; r < 4; ++r) {
        int m = m0 + (ty << 2) + r;
        if (m < M) {
            ushort4 v;
            v.x = f2bf(acc[r][0]);
            v.y = f2bf(acc[r][1]);
            v.z = f2bf(acc[r][2]);
            v.w = f2bf(acc[r][3]);
            *(ushort4*)&h[(size_t)m * DIM + bc] = v;
        }
    }
}

// ---------------- aggp: in-LDS counting sort + FULL-WAVE accumulation ------
// One block (512 thr) per 128-node partition; wave per node, lane l holds
// dims 2l,2l+1. Per edge: one 64x4B coalesced load + unpack-add.
__global__ __launch_bounds__(PT) void aggp(
    const ushortT* __restrict__ h, const int* __restrict__ pairs,
    const int* __restrict__ curD, float* __restrict__ out, int N) {
    __shared__ int sorted[CAPE];
    __shared__ int hist[PN], offs[PN], cur[PN];
    int p = blockIdx.x, tid = threadIdx.x;
    int wv = tid >> 6, l = tid & 63;
    if (tid < PN) hist[tid] = 0;
    __syncthreads();
    int cnt = min(curD[p], CAPE);
    const int* pb = &pairs[(size_t)p * CAPE];
    for (int i = tid; i < cnt; i += PT) atomicAdd(&hist[pb[i] & 127], 1);
    __syncthreads();
    if (tid < 64) {   // one wave scans 128 bins, 2 per lane
        int i0 = tid << 1;
        int x0 = hist[i0], x1 = hist[i0 + 1];
        int pairsum = x0 + x1;
        int incl = pairsum;
        for (int o = 1; o < 64; o <<= 1) {
            int y = __shfl_up(incl, o, 64);
            if (tid >= o) incl += y;
        }
        int excl = incl - pairsum;
        offs[i0] = excl;     offs[i0 + 1] = excl + x0;
        cur[i0]  = excl;     cur[i0 + 1]  = excl + x0;
    }
    __syncthreads();
    for (int i = tid; i < cnt; i += PT) {
        int w = pb[i];
        int slot = atomicAdd(&cur[w & 127], 1);
        if (slot < CAPE) sorted[slot] = w >> 7;
    }
    __syncthreads();
    for (int nd = wv; nd < PN; nd += 8) {       // full wave per node
        int node = p * PN + nd;
        if (node >= N) continue;
        int start = offs[nd];
        int degn = hist[nd];
        int end = min(start + degn, CAPE);
        float a0 = 0.f, a1 = 0.f;
        int e = start;
        for (; e + 4 <= end; e += 4) {
            int s0 = sorted[e],     s1 = sorted[e + 1];
            int s2 = sorted[e + 2], s3 = sorted[e + 3];
            uint u0 = *(const uint*)&h[(size_t)s0 * DIM + (l << 1)];
            uint u1 = *(const uint*)&h[(size_t)s1 * DIM + (l << 1)];
            uint u2 = *(const uint*)&h[(size_t)s2 * DIM + (l << 1)];
            uint u3 = *(const uint*)&h[(size_t)s3 * DIM + (l << 1)];
            a0 += (__uint_as_float(u0 << 16) + __uint_as_float(u1 << 16)) +
                  (__uint_as_float(u2 << 16) + __uint_as_float(u3 << 16));
            a1 += (__uint_as_float(u0 & 0xffff0000u) + __uint_as_float(u1 & 0xffff0000u)) +
                  (__uint_as_float(u2 & 0xffff0000u) + __uint_as_float(u3 & 0xffff0000u));
        }
        for (; e < end; ++e) {
            int s0 = sorted[e];
            uint u0 = *(const uint*)&h[(size_t)s0 * DIM + (l << 1)];
            a0 += __uint_as_float(u0 << 16);
            a1 += __uint_as_float(u0 & 0xffff0000u);
        }
        float sc = rsqrtf((float)max(degn, 1));
        *(float2*)&out[(size_t)node * DIM + (l << 1)] =
            make_float2(a0 * sc, a1 * sc);
    }
}

extern "C" void kernel_launch(void* const* d_in, const int* in_sizes, int n_in,
                              void* d_out, int out_size, void* d_ws, size_t ws_size,
                              hipStream_t stream) {
    const float* feat = (const float*)d_in[0];
    const float* W    = (const float*)d_in[1];
    const int*   src  = (const int*)d_in[2];
    const int*   dst  = (const int*)d_in[3];
    float* out = (float*)d_out;

    int N = in_sizes[0] / DIM;        // 100000
    int E = in_sizes[2];              // 1.6M
    int NPP = (N + PN - 1) / PN;      // 782 (<= MAXPP)

    // workspace layout
    int* curD = (int*)d_ws;                       // NPP
    int* curS = curD + NPP;                       // NPP
    float* oscale = (float*)(curS + NPP);         // N
    int* pairs = (int*)(oscale + N);              // NPP*CAPE
    unsigned char* srcb = (unsigned char*)(pairs + (size_t)NPP * CAPE);  // NPP*CAPS
    uintptr_t hp = (uintptr_t)(srcb + (size_t)NPP * CAPS);
    ushortT* h = (ushortT*)((hp + 15) & ~(uintptr_t)15);  // N*DIM bf16

    hipMemsetAsync(curD, 0, (size_t)2 * NPP * sizeof(int), stream);

    int nb = (E + CHUNK - 1) / CHUNK;   // 241
    part<<<nb, PT, 0, stream>>>(src, dst, curD, curS, pairs, srcb, E, NPP);
    deg<<<NPP, 256, 0, stream>>>(curS, srcb, oscale, N);
    gemm_h<<<(N + 31) / 32, 256, 0, stream>>>(feat, W, oscale, h, N);
    aggp<<<NPP, PT, 0, stream>>>(h, pairs, curD, out, N);
}